// Round 6
// baseline (6822.057 us; speedup 1.0000x reference)
//
#include <hip/hip_runtime.h>

// Problem dims (fixed by the reference)
constexpr int Bdim = 128;
constexpr int Tdim = 512;
constexpr int Fdim = 256;
constexpr int Hdim = 512;
constexpr int Kdim = Fdim + Hdim;       // 768 concat [x | h]
// Decomposition: 256 blocks = 16 bb (8 batch rows) x 16 jb (32 H-cols, all 4 gates)
constexpr int NB   = 8;                 // batch rows per block
constexpr int CC   = 128;               // concat-cols per block = 4 gates * 32 H-cols
constexpr int NC   = 8;                 // cols per thread
constexpr int NK   = 24;                // k per thread  (768 / 32 k-groups)
constexpr float EPSc = 1e-8f;
constexpr float CLAMPc = 10.0f;

// ws layout: hbuf u64[3][16][8][128] = 384 KB, triple-buffered packed-f16 h.
// Sentinel 0xFFFFFFFFFFFFFFFF is unreachable by packed h ( |h| < 1 strictly,
// so each f16 lane is never 0xFFFF ).
constexpr unsigned long long SENT = 0xFFFFFFFFFFFFFFFFull;
constexpr size_t HBUF_U64 = (size_t)3 * 16 * 8 * 128;

typedef _Float16 half2v __attribute__((ext_vector_type(2)));
typedef _Float16 half4v __attribute__((ext_vector_type(4)));
typedef unsigned long long u64x2 __attribute__((ext_vector_type(2)));

__device__ __forceinline__ float wave_sum4(float v) {
    // Sum across lanes {l, l^16, l^32, l^48} — the 4 k-subgroups in a wave.
    v += __shfl_xor(v, 16);
    v += __shfl_xor(v, 32);
    return v;
}

// 16B cache-bypassing load (L1+L2 bypass -> coherence point), for cross-XCD
// polling. Per-u64-half tear-safety is sufficient for the sentinel protocol.
__device__ __forceinline__ u64x2 load_b128_bypass(const unsigned long long* p) {
    u64x2 r;
    asm volatile("global_load_dwordx4 %0, %1, off sc0 sc1 nt\n\t"
                 "s_waitcnt vmcnt(0)"
                 : "=v"(r) : "v"(p) : "memory");
    return r;
}

__global__ __launch_bounds__(512, 2) void slstm_persist(
    const float* __restrict__ x,
    const float* __restrict__ Wf, const float* __restrict__ bfv,
    const float* __restrict__ Wi, const float* __restrict__ biv,
    const float* __restrict__ Wo, const float* __restrict__ bov,
    const float* __restrict__ Wz, const float* __restrict__ bzv,
    const float* __restrict__ Rf, const float* __restrict__ Ri,
    const float* __restrict__ Ro, const float* __restrict__ Rz,
    const float* __restrict__ fcw, const float* __restrict__ fcb,
    unsigned long long* hbuf,
    float* __restrict__ out)
{
    const int tid  = threadIdx.x;
    // XCD-aware swizzle (perf only; correctness never depends on placement —
    // the exchange goes through the device coherence point).
    const int xcd  = blockIdx.x & 7;
    const int slot = blockIdx.x >> 3;        // 0..31
    const int bb   = xcd * 2 + (slot & 1);   // 0..15
    const int jb   = slot >> 1;              // 0..15

    const int kg   = tid >> 4;               // 0..31 k-group
    const int colg = tid & 15;               // 0..15 col-group
    const int k0   = kg * NK;

    // ---------------- prologue: stationary weights -> f16 pair registers ----
    half2v wpk[NC][NK / 2];
    #pragma unroll
    for (int ci = 0; ci < NC; ++ci) {
        const int cc   = colg * NC + ci;         // 0..127
        const int g    = cc >> 5;                // gate
        const int hcol = jb * 32 + (cc & 31);    // global H column
        const float* Wg = (g == 0) ? Wf : (g == 1) ? Wi : (g == 2) ? Wo : Wz;
        const float* Rg = (g == 0) ? Rf : (g == 1) ? Ri : (g == 2) ? Ro : Rz;
        #pragma unroll
        for (int j = 0; j < NK / 2; ++j) {
            const int k = k0 + 2 * j;            // even; pair never spans 256
            float w0, w1;
            if (k < Fdim) {
                w0 = Wg[(size_t)k * Hdim + hcol];
                w1 = Wg[(size_t)(k + 1) * Hdim + hcol];
            } else {
                w0 = Rg[(size_t)(k - Fdim) * Hdim + hcol];
                w1 = Rg[(size_t)(k + 1 - Fdim) * Hdim + hcol];
            }
            wpk[ci][j] = half2v{(_Float16)w0, (_Float16)w1};   // RTN
        }
    }

    // cell-update thread identity (tid < 256): (ub, uhc)
    const int ub  = tid >> 5;                // 0..7
    const int uhc = tid & 31;                // 0..31
    float bias_f = 0.f, bias_i = 0.f, bias_o = 0.f, bias_z = 0.f;
    if (tid < 256) {
        bias_f = bfv[jb * 32 + uhc];
        bias_i = biv[jb * 32 + uhc];
        bias_o = bov[jb * 32 + uhc];
        bias_z = bzv[jb * 32 + uhc];
    }
    float c_st = 0.f, n_st = 0.f;

    // gather identity: (row, u0) — 512 threads x 16B cover 8 rows x 1KB
    const int grow = tid >> 6;               // 0..7
    const int gu0  = (tid & 63) * 2;         // even u64 index, 0..126

    __shared__ _Float16 in_s[NB][Kdim];          // 12 KB  f16 [x | h]
    __shared__ float    part_s[8][NB][CC];       // 32 KB  per-wave partials

    // ---- preamble: stage x_0 (f32->f16), zero h region ----
    {
        const int b  = tid >> 6;
        const int f4 = tid & 63;
        float4 v = *reinterpret_cast<const float4*>(
            x + ((size_t)(bb * NB + b) * Tdim + 0) * Fdim + f4 * 4);
        *reinterpret_cast<half4v*>(&in_s[b][f4 * 4]) =
            half4v{(_Float16)v.x, (_Float16)v.y, (_Float16)v.z, (_Float16)v.w};
        *reinterpret_cast<unsigned long long*>(&in_s[grow][Fdim + gu0 * 4])     = 0ull;
        *reinterpret_cast<unsigned long long*>(&in_s[grow][Fdim + gu0 * 4 + 4]) = 0ull;
    }
    __syncthreads();

    for (int t = 0; t < Tdim; ++t) {
        // ---- issue x_{t+1} prefetch into regs (latency hides under dot2) ----
        const int tn = (t + 1 < Tdim) ? (t + 1) : (Tdim - 1);
        float4 xnext = *reinterpret_cast<const float4*>(
            x + ((size_t)(bb * NB + (tid >> 6)) * Tdim + tn) * Fdim + (tid & 63) * 4);

        // ---- re-sentinel own slice of buf[(t+1)%3] (drained at barrier #1,
        //      hence visible strictly before this iter's h store) ----
        if (tid < 64) {
            hbuf[((((size_t)(t + 1) % 3) * 16 + bb) * 8 + (tid >> 3)) * 128
                 + jb * 8 + (tid & 7)] = SENT;   // plain store; barrier #1 orders it
        }

        // ---- dot2 inner loop: 384 fdot2 (768 MACs) per thread ----
        float acc[NC][NB];
        #pragma unroll
        for (int ci = 0; ci < NC; ++ci)
            #pragma unroll
            for (int b = 0; b < NB; ++b) acc[ci][b] = 0.f;

        #pragma unroll
        for (int b = 0; b < NB; ++b) {
            const half2v* p = reinterpret_cast<const half2v*>(&in_s[b][k0]);
            half2v hp[12];
            #pragma unroll
            for (int j = 0; j < 12; ++j) hp[j] = p[j];
            #pragma unroll
            for (int ci = 0; ci < NC; ++ci) {
                #pragma unroll
                for (int j = 0; j < NK / 2; ++j) {
                    acc[ci][b] = __builtin_amdgcn_fdot2(
                        wpk[ci][j], hp[j], acc[ci][b], false);
                }
            }
        }

        // ---- reduce across the 4 k-subgroups within the wave ----
        #pragma unroll
        for (int ci = 0; ci < NC; ++ci)
            #pragma unroll
            for (int b = 0; b < NB; ++b)
                acc[ci][b] = wave_sum4(acc[ci][b]);

        // each of the 4 duplicate lane-groups writes 2 batch rows
        {
            const int wv  = tid >> 6;
            const int kgl = (tid >> 4) & 3;
            #pragma unroll
            for (int bs = 0; bs < 2; ++bs) {
                const int b = kgl * 2 + bs;
                #pragma unroll
                for (int cp = 0; cp < NC / 2; ++cp) {
                    float2 w2 = make_float2(acc[2 * cp][b], acc[2 * cp + 1][b]);
                    *reinterpret_cast<float2*>(&part_s[wv][b][colg * NC + 2 * cp]) = w2;
                }
            }
        }
        __syncthreads();   // #1: dot2 LDS reads done; drains resets + x loads

        // ---- write x_{t+1} into in_s x-region (load long since returned) ----
        {
            *reinterpret_cast<half4v*>(&in_s[tid >> 6][(tid & 63) * 4]) =
                half4v{(_Float16)xnext.x, (_Float16)xnext.y,
                       (_Float16)xnext.z, (_Float16)xnext.w};
        }

        // ---- cross-wave reduce + bias + cell update + packed h store ----
        if (tid < 256) {
            float pre[4];
            #pragma unroll
            for (int g = 0; g < 4; ++g) {
                float s = 0.f;
                #pragma unroll
                for (int w = 0; w < 8; ++w) s += part_s[w][ub][g * 32 + uhc];
                pre[g] = s;
            }
            pre[0] += bias_f; pre[1] += bias_i; pre[2] += bias_o; pre[3] += bias_z;

            float o  = 1.0f / (1.0f + __expf(-pre[2]));
            float z  = tanhf(pre[3]);
            float fh = __expf(fminf(pre[0], CLAMPc));
            float ih = __expf(fminf(pre[1], CLAMPc));
            float denom = fh + ih + EPSc;
            float f  = fh / denom;
            float ii = ih / denom;
            c_st = f * c_st + ii * z;
            n_st = f * n_st + ii;
            float hval = o * (c_st / (n_st + EPSc));

            // pack 4 cols -> u64 (waves 0-3 fully active; shfl well-defined)
            float h1 = __shfl_xor(hval, 1);
            half2v hp2 = half2v{(_Float16)hval, (_Float16)h1};
            unsigned pck = __builtin_bit_cast(unsigned, hp2);
            unsigned qck = (unsigned)__shfl_xor((int)pck, 2);
            if ((uhc & 3) == 0) {
                unsigned long long v64 =
                    (unsigned long long)pck | ((unsigned long long)qck << 32);
                __hip_atomic_store(
                    &hbuf[(((size_t)(t % 3) * 16 + bb) * 8 + ub) * 128
                          + ((jb * 32 + uhc) >> 2)],
                    v64, __ATOMIC_RELAXED, __HIP_MEMORY_SCOPE_AGENT);
            }
        }

        // ---- poll + gather h_t directly (data words ARE the flags) ----
        {
            const unsigned long long* src =
                &hbuf[(((size_t)(t % 3) * 16 + bb) * 8 + grow) * 128 + gu0];
            u64x2 v;
            do {
                v = load_b128_bypass(src);
            } while (v.x == SENT || v.y == SENT);
            *reinterpret_cast<unsigned long long*>(&in_s[grow][Fdim + gu0 * 4])     = v.x;
            *reinterpret_cast<unsigned long long*>(&in_s[grow][Fdim + gu0 * 4 + 4]) = v.y;
        }
        __syncthreads();   // #2: gathered h + staged x visible to next dot2
    }

    // ---- final fc from in_s (final h, f16): out[b] = tanh(h . fc_w + fc_b) ----
    if (jb == 0) {
        const int w = tid >> 6;              // one wave per batch row
        const int l = tid & 63;
        float p = 0.f;
        #pragma unroll
        for (int s = 0; s < 8; ++s)
            p += (float)in_s[w][Fdim + l + s * 64] * fcw[l + s * 64];
        p += __shfl_xor(p, 32);
        p += __shfl_xor(p, 16);
        p += __shfl_xor(p, 8);
        p += __shfl_xor(p, 4);
        p += __shfl_xor(p, 2);
        p += __shfl_xor(p, 1);
        if (l == 0) out[bb * NB + w] = tanhf(p + fcb[0]);
    }
}

extern "C" void kernel_launch(void* const* d_in, const int* in_sizes, int n_in,
                              void* d_out, int out_size, void* d_ws, size_t ws_size,
                              hipStream_t stream) {
    const float* x   = (const float*)d_in[0];
    const float* Wf  = (const float*)d_in[1];
    const float* bf_ = (const float*)d_in[2];
    const float* Wi  = (const float*)d_in[3];
    const float* bi_ = (const float*)d_in[4];
    const float* Wo  = (const float*)d_in[5];
    const float* bo_ = (const float*)d_in[6];
    const float* Wz  = (const float*)d_in[7];
    const float* bz_ = (const float*)d_in[8];
    const float* Rf  = (const float*)d_in[9];
    const float* Ri  = (const float*)d_in[10];
    const float* Ro  = (const float*)d_in[11];
    const float* Rz  = (const float*)d_in[12];
    const float* fcw = (const float*)d_in[13];
    const float* fcb = (const float*)d_in[14];

    unsigned long long* hbuf = (unsigned long long*)d_ws;
    float* o = (float*)d_out;

    // Pre-sentinel the whole exchange buffer (0xFF bytes) — gives t=0..2
    // validity with no startup rendezvous. Captured in the graph, so it
    // re-runs before every replay (ws is re-poisoned 0xAA by the harness).
    hipMemsetAsync(d_ws, 0xFF, HBUF_U64 * sizeof(unsigned long long), stream);

    void* args[] = { &x, &Wf, &bf_, &Wi, &bi_, &Wo, &bo_, &Wz, &bz_,
                     &Rf, &Ri, &Ro, &Rz, &fcw, &fcb, &hbuf, &o };

    hipLaunchCooperativeKernel(reinterpret_cast<void*>(slstm_persist),
                               dim3(256), dim3(512), args, 0, stream);
}